// Round 1
// baseline (2077.275 us; speedup 1.0000x reference)
//
#include <hip/hip_runtime.h>
#include <math.h>

#define LSEQ   2048
#define DMODEL 1024
#define DINNER 2048
#define DSTATE 16
#define DTRANK 64
#define XCOLS  96   // dt_rank + 2*d_state

__device__ __forceinline__ float siluf(float v) { return v / (1.f + __expf(-v)); }

// ---------------------------------------------------------------------------
// 128x128 tile fp32 GEMM: C[M,N] = A[M,K] * B[N,K]^T   (both K-contiguous)
// 256 threads, 8x8 per thread. Dims must satisfy K%16==0, N%8==0 here.
// ---------------------------------------------------------------------------
__global__ __launch_bounds__(256)
void gemm128(const float* __restrict__ A, int lda,
             const float* __restrict__ B, int ldb,
             float* __restrict__ C, int ldc,
             int M, int N, int K)
{
    __shared__ float As[16][132];
    __shared__ float Bs[16][132];
    const int tid = threadIdx.x;
    const int m0 = blockIdx.x * 128;
    const int n0 = blockIdx.y * 128;
    const int lr = tid >> 1;          // 0..127 row within tile
    const int lk = (tid & 1) * 8;     // k offset 0 or 8
    const int tm = tid >> 4;          // 0..15
    const int tn = tid & 15;          // 0..15

    float acc[8][8];
#pragma unroll
    for (int i = 0; i < 8; i++)
#pragma unroll
        for (int j = 0; j < 8; j++) acc[i][j] = 0.f;

    const bool am = (m0 + lr) < M;
    const bool bn = (n0 + lr) < N;
    const float* Arow = A + (size_t)(m0 + lr) * lda;
    const float* Brow = B + (size_t)(n0 + lr) * ldb;

    for (int k0 = 0; k0 < K; k0 += 16) {
        float4 a0 = make_float4(0,0,0,0), a1 = make_float4(0,0,0,0);
        float4 b0 = make_float4(0,0,0,0), b1 = make_float4(0,0,0,0);
        if (am) {
            a0 = *(const float4*)(Arow + k0 + lk);
            a1 = *(const float4*)(Arow + k0 + lk + 4);
        }
        if (bn) {
            b0 = *(const float4*)(Brow + k0 + lk);
            b1 = *(const float4*)(Brow + k0 + lk + 4);
        }
        __syncthreads();
        As[lk+0][lr]=a0.x; As[lk+1][lr]=a0.y; As[lk+2][lr]=a0.z; As[lk+3][lr]=a0.w;
        As[lk+4][lr]=a1.x; As[lk+5][lr]=a1.y; As[lk+6][lr]=a1.z; As[lk+7][lr]=a1.w;
        Bs[lk+0][lr]=b0.x; Bs[lk+1][lr]=b0.y; Bs[lk+2][lr]=b0.z; Bs[lk+3][lr]=b0.w;
        Bs[lk+4][lr]=b1.x; Bs[lk+5][lr]=b1.y; Bs[lk+6][lr]=b1.z; Bs[lk+7][lr]=b1.w;
        __syncthreads();
#pragma unroll
        for (int kk = 0; kk < 16; kk++) {
            float a_[8], b_[8];
            *(float4*)&a_[0] = *(const float4*)&As[kk][tm*8];
            *(float4*)&a_[4] = *(const float4*)&As[kk][tm*8+4];
            *(float4*)&b_[0] = *(const float4*)&Bs[kk][tn*8];
            *(float4*)&b_[4] = *(const float4*)&Bs[kk][tn*8+4];
#pragma unroll
            for (int i = 0; i < 8; i++)
#pragma unroll
                for (int j = 0; j < 8; j++)
                    acc[i][j] = fmaf(a_[i], b_[j], acc[i][j]);
        }
    }

#pragma unroll
    for (int i = 0; i < 8; i++) {
        int m = m0 + tm*8 + i;
        if (m >= M) continue;
        float* Crow = C + (size_t)m * ldc + n0 + tn*8;
        if (n0 + tn*8 + 7 < N) {
            *(float4*)(Crow)   = make_float4(acc[i][0], acc[i][1], acc[i][2], acc[i][3]);
            *(float4*)(Crow+4) = make_float4(acc[i][4], acc[i][5], acc[i][6], acc[i][7]);
        } else {
#pragma unroll
            for (int j = 0; j < 8; j++)
                if (n0 + tn*8 + j < N) Crow[j] = acc[i][j];
        }
    }
}

// ---------------------------------------------------------------------------
// 64x64 tile fp32 GEMM, 4x4 per thread, optional split-K (atomicAdd) and
// optional bias+softplus epilogue. C[M,N] = A[M,K]*B[N,K]^T.
// ---------------------------------------------------------------------------
template<int EPI, int SPLITK>
__global__ __launch_bounds__(256)
void gemm64(const float* __restrict__ A, int lda,
            const float* __restrict__ B, int ldb,
            float* C, int ldc,
            const float* __restrict__ bias,
            int M, int N, int K, int KC)
{
    __shared__ float As[16][68];
    __shared__ float Bs[16][68];
    const int tid = threadIdx.x;
    const int m0 = blockIdx.x * 64;
    const int n0 = blockIdx.y * 64;
    const int kbeg = SPLITK ? blockIdx.z * KC : 0;
    const int kend = SPLITK ? min(K, kbeg + KC) : K;
    const int lr = tid >> 2;         // 0..63
    const int lq = (tid & 3) * 4;    // 0,4,8,12
    const int tm = tid >> 4;
    const int tn = tid & 15;

    float acc[4][4];
#pragma unroll
    for (int i = 0; i < 4; i++)
#pragma unroll
        for (int j = 0; j < 4; j++) acc[i][j] = 0.f;

    const bool am = (m0 + lr) < M;
    const bool bn = (n0 + lr) < N;
    const float* Arow = A + (size_t)(m0 + lr) * lda;
    const float* Brow = B + (size_t)(n0 + lr) * ldb;

    for (int k0 = kbeg; k0 < kend; k0 += 16) {
        float4 va = am ? *(const float4*)(Arow + k0 + lq) : make_float4(0,0,0,0);
        float4 vb = bn ? *(const float4*)(Brow + k0 + lq) : make_float4(0,0,0,0);
        __syncthreads();
        As[lq+0][lr]=va.x; As[lq+1][lr]=va.y; As[lq+2][lr]=va.z; As[lq+3][lr]=va.w;
        Bs[lq+0][lr]=vb.x; Bs[lq+1][lr]=vb.y; Bs[lq+2][lr]=vb.z; Bs[lq+3][lr]=vb.w;
        __syncthreads();
#pragma unroll
        for (int kk = 0; kk < 16; kk++) {
            float a_[4], b_[4];
#pragma unroll
            for (int i = 0; i < 4; i++) { a_[i] = As[kk][tm*4+i]; b_[i] = Bs[kk][tn*4+i]; }
#pragma unroll
            for (int i = 0; i < 4; i++)
#pragma unroll
                for (int j = 0; j < 4; j++)
                    acc[i][j] = fmaf(a_[i], b_[j], acc[i][j]);
        }
    }

#pragma unroll
    for (int i = 0; i < 4; i++) {
        int m = m0 + tm*4 + i;
        if (m >= M) continue;
#pragma unroll
        for (int j = 0; j < 4; j++) {
            int n = n0 + tn*4 + j;
            if (n >= N) continue;
            float c = acc[i][j];
            if (SPLITK) {
                atomicAdd(&C[(size_t)m * ldc + n], c);
            } else {
                if (EPI == 1) {
                    c += bias[n];
                    c = (c > 20.f) ? c : log1pf(__expf(c));
                }
                C[(size_t)m * ldc + n] = c;
            }
        }
    }
}

// ---------------------------------------------------------------------------
// Depthwise causal conv (width 4) + bias + SiLU.
// x_in = xz[:, 0:DINNER];  xc[t][d] = silu(sum_j w[d][j]*x_in[t-3+j][d] + b[d])
// ---------------------------------------------------------------------------
__global__ __launch_bounds__(256)
void conv_silu_kernel(const float* __restrict__ xz,
                      const float* __restrict__ conv_w,
                      const float* __restrict__ conv_b,
                      float* __restrict__ xc)
{
    int idx = blockIdx.x * 256 + threadIdx.x;
    if (idx >= LSEQ * DINNER) return;
    int t = idx / DINNER;
    int d = idx - t * DINNER;
    float acc = conv_b[d];
#pragma unroll
    for (int j = 0; j < 4; j++) {
        int tt = t - 3 + j;
        if (tt >= 0) acc = fmaf(conv_w[d*4 + j], xz[(size_t)tt * (2*DINNER) + d], acc);
    }
    xc[idx] = siluf(acc);
}

// ---------------------------------------------------------------------------
// Selective scan. One lane per (channel d, state n). 16-lane groups.
// h = exp(dt*A)*h + dt*B*x ;  y = sum_n h*C ; fused: y = (y + D*x)*silu(z)
// y written in place over xc (read of xc[t][d] happens before write each t).
// ---------------------------------------------------------------------------
__global__ __launch_bounds__(256)
void scan_kernel(const float* __restrict__ dtm,
                 const float* __restrict__ xdbl,
                 const float* xcin,
                 const float* __restrict__ A_log,
                 const float* __restrict__ Dp,
                 const float* __restrict__ xz,
                 float* y)
{
    const int tid = threadIdx.x;
    const int d = blockIdx.x * 16 + (tid >> 4);
    const int n = tid & 15;
    const float a  = -__expf(A_log[d * DSTATE + n]);
    const float Dv = Dp[d];
    float h = 0.f;
    for (int t = 0; t < LSEQ; t++) {
        float dtv = dtm[(size_t)t * DINNER + d];
        float xv  = xcin[(size_t)t * DINNER + d];
        float Bv  = xdbl[t * XCOLS + DTRANK + n];
        float Cv  = xdbl[t * XCOLS + DTRANK + DSTATE + n];
        h = fmaf(__expf(dtv * a), h, dtv * Bv * xv);
        float p = h * Cv;
        p += __shfl_xor(p, 1);
        p += __shfl_xor(p, 2);
        p += __shfl_xor(p, 4);
        p += __shfl_xor(p, 8);
        if (n == 0) {
            float zv = xz[(size_t)t * (2*DINNER) + DINNER + d];
            y[(size_t)t * DINNER + d] = (p + Dv * xv) * siluf(zv);
        }
    }
}

// ---------------------------------------------------------------------------
extern "C" void kernel_launch(void* const* d_in, const int* in_sizes, int n_in,
                              void* d_out, int out_size, void* d_ws, size_t ws_size,
                              hipStream_t stream)
{
    const float* x      = (const float*)d_in[0];
    const float* W_in   = (const float*)d_in[1];
    const float* conv_w = (const float*)d_in[2];
    const float* conv_b = (const float*)d_in[3];
    const float* W_x    = (const float*)d_in[4];
    const float* W_dt   = (const float*)d_in[5];
    const float* b_dt   = (const float*)d_in[6];
    const float* A_log  = (const float*)d_in[7];
    const float* D_par  = (const float*)d_in[8];
    const float* W_out  = (const float*)d_in[9];
    float* out = (float*)d_out;
    float* ws  = (float*)d_ws;

    float* xz   = ws;                                   // 2048*4096
    float* xc   = ws + (size_t)LSEQ * 2 * DINNER;       // 2048*2048 (also y)
    float* xdbl = xc + (size_t)LSEQ * DINNER;           // 2048*96
    float* dtm  = xdbl + (size_t)LSEQ * XCOLS;          // 2048*2048

    // 1. in_proj: xz = x @ W_in^T   (2048 x 4096)
    hipLaunchKernelGGL(gemm128, dim3(LSEQ/128, (2*DINNER)/128), dim3(256), 0, stream,
                       x, DMODEL, W_in, DMODEL, xz, 2*DINNER, LSEQ, 2*DINNER, DMODEL);

    // 2. depthwise conv + SiLU -> xc
    hipLaunchKernelGGL(conv_silu_kernel, dim3((LSEQ*DINNER)/256), dim3(256), 0, stream,
                       xz, conv_w, conv_b, xc);

    // 3. x_dbl = xc @ W_x^T  (2048 x 96), split-K over 8 chunks
    hipMemsetAsync(xdbl, 0, (size_t)LSEQ * XCOLS * sizeof(float), stream);
    hipLaunchKernelGGL((gemm64<0,1>), dim3(LSEQ/64, 2, 8), dim3(256), 0, stream,
                       xc, DINNER, W_x, DINNER, xdbl, XCOLS, (const float*)nullptr,
                       LSEQ, XCOLS, DINNER, 256);

    // 4. dt = softplus(x_dbl[:, :64] @ W_dt^T + b_dt)  (2048 x 2048)
    hipLaunchKernelGGL((gemm64<1,0>), dim3(LSEQ/64, DINNER/64, 1), dim3(256), 0, stream,
                       xdbl, XCOLS, W_dt, DTRANK, dtm, DINNER, b_dt,
                       LSEQ, DINNER, DTRANK, 0);

    // 5. selective scan (y overwrites xc in place), fused D-skip + z-gate
    hipLaunchKernelGGL(scan_kernel, dim3(DINNER/16), dim3(256), 0, stream,
                       dtm, xdbl, xc, A_log, D_par, xz, xc);

    // 6. out = y @ W_out^T  (2048 x 1024)
    hipLaunchKernelGGL(gemm128, dim3(LSEQ/128, DMODEL/128), dim3(256), 0, stream,
                       xc, DINNER, W_out, DINNER, out, DMODEL, LSEQ, DMODEL, DINNER);
}

// Round 2
// 697.194 us; speedup vs baseline: 2.9795x; 2.9795x over previous
//
#include <hip/hip_runtime.h>
#include <math.h>

#define LSEQ   2048
#define DMODEL 1024
#define DINNER 2048
#define DSTATE 16
#define DTRANK 64
#define XCOLS  96   // dt_rank + 2*d_state
#define CL     64   // scan chunk length
#define NC     (LSEQ/CL)          // 32 chunks
#define SSTATE (DINNER*DSTATE)    // 32768 scalar recurrences

__device__ __forceinline__ float siluf(float v) { return v / (1.f + __expf(-v)); }

// ---------------------------------------------------------------------------
// 128x128 tile fp32 GEMM: C[M,N] = A[M,K] * B[N,K]^T   (both K-contiguous)
// ---------------------------------------------------------------------------
__global__ __launch_bounds__(256)
void gemm128(const float* __restrict__ A, int lda,
             const float* __restrict__ B, int ldb,
             float* __restrict__ C, int ldc,
             int M, int N, int K)
{
    __shared__ float As[16][132];
    __shared__ float Bs[16][132];
    const int tid = threadIdx.x;
    const int m0 = blockIdx.x * 128;
    const int n0 = blockIdx.y * 128;
    const int lr = tid >> 1;
    const int lk = (tid & 1) * 8;
    const int tm = tid >> 4;
    const int tn = tid & 15;

    float acc[8][8];
#pragma unroll
    for (int i = 0; i < 8; i++)
#pragma unroll
        for (int j = 0; j < 8; j++) acc[i][j] = 0.f;

    const bool am = (m0 + lr) < M;
    const bool bn = (n0 + lr) < N;
    const float* Arow = A + (size_t)(m0 + lr) * lda;
    const float* Brow = B + (size_t)(n0 + lr) * ldb;

    for (int k0 = 0; k0 < K; k0 += 16) {
        float4 a0 = make_float4(0,0,0,0), a1 = make_float4(0,0,0,0);
        float4 b0 = make_float4(0,0,0,0), b1 = make_float4(0,0,0,0);
        if (am) {
            a0 = *(const float4*)(Arow + k0 + lk);
            a1 = *(const float4*)(Arow + k0 + lk + 4);
        }
        if (bn) {
            b0 = *(const float4*)(Brow + k0 + lk);
            b1 = *(const float4*)(Brow + k0 + lk + 4);
        }
        __syncthreads();
        As[lk+0][lr]=a0.x; As[lk+1][lr]=a0.y; As[lk+2][lr]=a0.z; As[lk+3][lr]=a0.w;
        As[lk+4][lr]=a1.x; As[lk+5][lr]=a1.y; As[lk+6][lr]=a1.z; As[lk+7][lr]=a1.w;
        Bs[lk+0][lr]=b0.x; Bs[lk+1][lr]=b0.y; Bs[lk+2][lr]=b0.z; Bs[lk+3][lr]=b0.w;
        Bs[lk+4][lr]=b1.x; Bs[lk+5][lr]=b1.y; Bs[lk+6][lr]=b1.z; Bs[lk+7][lr]=b1.w;
        __syncthreads();
#pragma unroll
        for (int kk = 0; kk < 16; kk++) {
            float a_[8], b_[8];
            *(float4*)&a_[0] = *(const float4*)&As[kk][tm*8];
            *(float4*)&a_[4] = *(const float4*)&As[kk][tm*8+4];
            *(float4*)&b_[0] = *(const float4*)&Bs[kk][tn*8];
            *(float4*)&b_[4] = *(const float4*)&Bs[kk][tn*8+4];
#pragma unroll
            for (int i = 0; i < 8; i++)
#pragma unroll
                for (int j = 0; j < 8; j++)
                    acc[i][j] = fmaf(a_[i], b_[j], acc[i][j]);
        }
    }

#pragma unroll
    for (int i = 0; i < 8; i++) {
        int m = m0 + tm*8 + i;
        if (m >= M) continue;
        float* Crow = C + (size_t)m * ldc + n0 + tn*8;
        if (n0 + tn*8 + 7 < N) {
            *(float4*)(Crow)   = make_float4(acc[i][0], acc[i][1], acc[i][2], acc[i][3]);
            *(float4*)(Crow+4) = make_float4(acc[i][4], acc[i][5], acc[i][6], acc[i][7]);
        } else {
#pragma unroll
            for (int j = 0; j < 8; j++)
                if (n0 + tn*8 + j < N) Crow[j] = acc[i][j];
        }
    }
}

// ---------------------------------------------------------------------------
// 64x64 tile fp32 GEMM, optional split-K (atomicAdd) / bias+softplus epilogue
// ---------------------------------------------------------------------------
template<int EPI, int SPLITK>
__global__ __launch_bounds__(256)
void gemm64(const float* __restrict__ A, int lda,
            const float* __restrict__ B, int ldb,
            float* C, int ldc,
            const float* __restrict__ bias,
            int M, int N, int K, int KC)
{
    __shared__ float As[16][68];
    __shared__ float Bs[16][68];
    const int tid = threadIdx.x;
    const int m0 = blockIdx.x * 64;
    const int n0 = blockIdx.y * 64;
    const int kbeg = SPLITK ? blockIdx.z * KC : 0;
    const int kend = SPLITK ? min(K, kbeg + KC) : K;
    const int lr = tid >> 2;
    const int lq = (tid & 3) * 4;
    const int tm = tid >> 4;
    const int tn = tid & 15;

    float acc[4][4];
#pragma unroll
    for (int i = 0; i < 4; i++)
#pragma unroll
        for (int j = 0; j < 4; j++) acc[i][j] = 0.f;

    const bool am = (m0 + lr) < M;
    const bool bn = (n0 + lr) < N;
    const float* Arow = A + (size_t)(m0 + lr) * lda;
    const float* Brow = B + (size_t)(n0 + lr) * ldb;

    for (int k0 = kbeg; k0 < kend; k0 += 16) {
        float4 va = am ? *(const float4*)(Arow + k0 + lq) : make_float4(0,0,0,0);
        float4 vb = bn ? *(const float4*)(Brow + k0 + lq) : make_float4(0,0,0,0);
        __syncthreads();
        As[lq+0][lr]=va.x; As[lq+1][lr]=va.y; As[lq+2][lr]=va.z; As[lq+3][lr]=va.w;
        Bs[lq+0][lr]=vb.x; Bs[lq+1][lr]=vb.y; Bs[lq+2][lr]=vb.z; Bs[lq+3][lr]=vb.w;
        __syncthreads();
#pragma unroll
        for (int kk = 0; kk < 16; kk++) {
            float a_[4], b_[4];
#pragma unroll
            for (int i = 0; i < 4; i++) { a_[i] = As[kk][tm*4+i]; b_[i] = Bs[kk][tn*4+i]; }
#pragma unroll
            for (int i = 0; i < 4; i++)
#pragma unroll
                for (int j = 0; j < 4; j++)
                    acc[i][j] = fmaf(a_[i], b_[j], acc[i][j]);
        }
    }

#pragma unroll
    for (int i = 0; i < 4; i++) {
        int m = m0 + tm*4 + i;
        if (m >= M) continue;
#pragma unroll
        for (int j = 0; j < 4; j++) {
            int n = n0 + tn*4 + j;
            if (n >= N) continue;
            float c = acc[i][j];
            if (SPLITK) {
                atomicAdd(&C[(size_t)m * ldc + n], c);
            } else {
                if (EPI == 1) {
                    c += bias[n];
                    c = (c > 20.f) ? c : log1pf(__expf(c));
                }
                C[(size_t)m * ldc + n] = c;
            }
        }
    }
}

// ---------------------------------------------------------------------------
// Depthwise causal conv (width 4) + bias + SiLU.
// ---------------------------------------------------------------------------
__global__ __launch_bounds__(256)
void conv_silu_kernel(const float* __restrict__ xz,
                      const float* __restrict__ conv_w,
                      const float* __restrict__ conv_b,
                      float* __restrict__ xc)
{
    int idx = blockIdx.x * 256 + threadIdx.x;
    if (idx >= LSEQ * DINNER) return;
    int t = idx / DINNER;
    int d = idx - t * DINNER;
    float acc = conv_b[d];
#pragma unroll
    for (int j = 0; j < 4; j++) {
        int tt = t - 3 + j;
        if (tt >= 0) acc = fmaf(conv_w[d*4 + j], xz[(size_t)tt * (2*DINNER) + d], acc);
    }
    xc[idx] = siluf(acc);
}

// ---------------------------------------------------------------------------
// Chunked parallel selective scan.
// Recurrence per (d,n):  h_t = a_t h_{t-1} + b_t,  a_t=exp(dt*A), b_t=dt*B*x.
// Phase 1: per chunk, local scan from 0 -> hend, and Aprod = prod a_t.
// Phase 2: sequential over NC chunks per (d,n): hend[c] <- carry-in of chunk c.
// Phase 3: re-scan chunk from carry-in, contract with C over n, gate, store y.
// ---------------------------------------------------------------------------
__global__ __launch_bounds__(256)
void scan_phase1(const float* __restrict__ dtm,
                 const float* __restrict__ xdbl,
                 const float* __restrict__ xc,
                 const float* __restrict__ A_log,
                 float* __restrict__ Aprod, float* __restrict__ hend)
{
    const int tid = threadIdx.x;
    const int n = tid & 15;
    const int d = blockIdx.x * 16 + (tid >> 4);
    const int c = blockIdx.y;
    const float a_ = -__expf(A_log[d * DSTATE + n]);
    float h = 0.f, Ap = 1.f;
    const int t0 = c * CL;
#pragma unroll 4
    for (int t = t0; t < t0 + CL; t++) {
        float dtv = dtm[(size_t)t * DINNER + d];
        float xv  = xc[(size_t)t * DINNER + d];
        float Bv  = xdbl[t * XCOLS + DTRANK + n];
        float e = __expf(dtv * a_);
        h = fmaf(e, h, dtv * Bv * xv);
        Ap *= e;
    }
    const size_t idx = (size_t)c * SSTATE + d * DSTATE + n;
    Aprod[idx] = Ap;
    hend[idx]  = h;
}

__global__ __launch_bounds__(256)
void scan_phase2(const float* __restrict__ Aprod, float* __restrict__ hend)
{
    const int idx = blockIdx.x * 256 + threadIdx.x;   // 0..SSTATE-1
    float carry = 0.f;
#pragma unroll
    for (int c = 0; c < NC; c++) {
        const size_t k = (size_t)c * SSTATE + idx;
        float oh = hend[k];
        float oA = Aprod[k];
        hend[k] = carry;                 // carry-in for chunk c
        carry = fmaf(oA, carry, oh);
    }
}

__global__ __launch_bounds__(256)
void scan_phase3(const float* __restrict__ dtm,
                 const float* __restrict__ xdbl,
                 const float* xcin,
                 const float* __restrict__ A_log,
                 const float* __restrict__ Dp,
                 const float* __restrict__ xz,
                 const float* __restrict__ hinit,
                 float* y)
{
    const int tid = threadIdx.x;
    const int n = tid & 15;
    const int d = blockIdx.x * 16 + (tid >> 4);
    const int c = blockIdx.y;
    const float a_ = -__expf(A_log[d * DSTATE + n]);
    const float Dv = Dp[d];
    float h = hinit[(size_t)c * SSTATE + d * DSTATE + n];
    const int t0 = c * CL;
    for (int t = t0; t < t0 + CL; t++) {
        float dtv = dtm[(size_t)t * DINNER + d];
        float xv  = xcin[(size_t)t * DINNER + d];
        float Bv  = xdbl[t * XCOLS + DTRANK + n];
        float Cv  = xdbl[t * XCOLS + DTRANK + DSTATE + n];
        h = fmaf(__expf(dtv * a_), h, dtv * Bv * xv);
        float p = h * Cv;
        p += __shfl_xor(p, 1);
        p += __shfl_xor(p, 2);
        p += __shfl_xor(p, 4);
        p += __shfl_xor(p, 8);
        if (n == 0) {
            float zv = xz[(size_t)t * (2*DINNER) + DINNER + d];
            y[(size_t)t * DINNER + d] = (p + Dv * xv) * siluf(zv);
        }
    }
}

// ---------------------------------------------------------------------------
extern "C" void kernel_launch(void* const* d_in, const int* in_sizes, int n_in,
                              void* d_out, int out_size, void* d_ws, size_t ws_size,
                              hipStream_t stream)
{
    const float* x      = (const float*)d_in[0];
    const float* W_in   = (const float*)d_in[1];
    const float* conv_w = (const float*)d_in[2];
    const float* conv_b = (const float*)d_in[3];
    const float* W_x    = (const float*)d_in[4];
    const float* W_dt   = (const float*)d_in[5];
    const float* b_dt   = (const float*)d_in[6];
    const float* A_log  = (const float*)d_in[7];
    const float* D_par  = (const float*)d_in[8];
    const float* W_out  = (const float*)d_in[9];
    float* out = (float*)d_out;
    float* ws  = (float*)d_ws;

    float* xz    = ws;                                   // 2048*4096
    float* xc    = xz   + (size_t)LSEQ * 2 * DINNER;     // 2048*2048 (also y)
    float* xdbl  = xc   + (size_t)LSEQ * DINNER;         // 2048*96
    float* dtm   = xdbl + (size_t)LSEQ * XCOLS;          // 2048*2048
    float* Aprod = dtm  + (size_t)LSEQ * DINNER;         // NC*SSTATE = 1M
    float* hend  = Aprod + (size_t)NC * SSTATE;          // NC*SSTATE = 1M

    // 1. in_proj: xz = x @ W_in^T   (2048 x 4096)
    hipLaunchKernelGGL(gemm128, dim3(LSEQ/128, (2*DINNER)/128), dim3(256), 0, stream,
                       x, DMODEL, W_in, DMODEL, xz, 2*DINNER, LSEQ, 2*DINNER, DMODEL);

    // 2. depthwise conv + SiLU -> xc
    hipLaunchKernelGGL(conv_silu_kernel, dim3((LSEQ*DINNER)/256), dim3(256), 0, stream,
                       xz, conv_w, conv_b, xc);

    // 3. x_dbl = xc @ W_x^T  (2048 x 96), split-K over 8 chunks
    hipMemsetAsync(xdbl, 0, (size_t)LSEQ * XCOLS * sizeof(float), stream);
    hipLaunchKernelGGL((gemm64<0,1>), dim3(LSEQ/64, 2, 8), dim3(256), 0, stream,
                       xc, DINNER, W_x, DINNER, xdbl, XCOLS, (const float*)nullptr,
                       LSEQ, XCOLS, DINNER, 256);

    // 4. dt = softplus(x_dbl[:, :64] @ W_dt^T + b_dt)  (2048 x 2048)
    hipLaunchKernelGGL((gemm64<1,0>), dim3(LSEQ/64, DINNER/64, 1), dim3(256), 0, stream,
                       xdbl, XCOLS, W_dt, DTRANK, dtm, DINNER, b_dt,
                       LSEQ, DINNER, DTRANK, 0);

    // 5. chunked parallel scan (y overwrites xc), fused D-skip + z-gate
    hipLaunchKernelGGL(scan_phase1, dim3(DINNER/16, NC), dim3(256), 0, stream,
                       dtm, xdbl, xc, A_log, Aprod, hend);
    hipLaunchKernelGGL(scan_phase2, dim3(SSTATE/256), dim3(256), 0, stream,
                       Aprod, hend);
    hipLaunchKernelGGL(scan_phase3, dim3(DINNER/16, NC), dim3(256), 0, stream,
                       dtm, xdbl, xc, A_log, D_par, xz, hend, xc);

    // 6. out = y @ W_out^T  (2048 x 1024)
    hipLaunchKernelGGL(gemm128, dim3(LSEQ/128, DMODEL/128), dim3(256), 0, stream,
                       xc, DINNER, W_out, DINNER, out, DMODEL, LSEQ, DMODEL, DINNER);
}

// Round 3
// 321.107 us; speedup vs baseline: 6.4691x; 2.1712x over previous
//
#include <hip/hip_runtime.h>
#include <math.h>

#define LSEQ   2048
#define DMODEL 1024
#define DINNER 2048
#define DSTATE 16
#define DTRANK 64
#define XCOLS  96   // dt_rank + 2*d_state
#define CL     64   // scan chunk length
#define NC     (LSEQ/CL)          // 32 chunks
#define SSTATE (DINNER*DSTATE)    // 32768 scalar recurrences

typedef __attribute__((ext_vector_type(8))) short bf16x8;
typedef __attribute__((ext_vector_type(4))) float f32x4;
typedef unsigned short ushort_t;
typedef unsigned int uint_t;

__device__ __forceinline__ float siluf(float v) { return v / (1.f + __expf(-v)); }

// RNE float -> bf16 bits (finite inputs)
__device__ __forceinline__ ushort_t f2bf(float f) {
    uint_t u = __float_as_uint(f);
    u += 0x7FFFu + ((u >> 16) & 1u);
    return (ushort_t)(u >> 16);
}

// ---------------------------------------------------------------------------
// f32 -> bf16 cast, 8 elements/thread. n % 8 == 0.
// ---------------------------------------------------------------------------
__global__ __launch_bounds__(256)
void cast_bf16_kernel(const float* __restrict__ in, ushort_t* __restrict__ outp, int n)
{
    int i = (blockIdx.x * 256 + threadIdx.x) * 8;
    if (i >= n) return;
    float4 v0 = *(const float4*)(in + i);
    float4 v1 = *(const float4*)(in + i + 4);
    bf16x8 r;
    r[0] = (short)f2bf(v0.x); r[1] = (short)f2bf(v0.y);
    r[2] = (short)f2bf(v0.z); r[3] = (short)f2bf(v0.w);
    r[4] = (short)f2bf(v1.x); r[5] = (short)f2bf(v1.y);
    r[6] = (short)f2bf(v1.z); r[7] = (short)f2bf(v1.w);
    *(bf16x8*)(outp + i) = r;
}

// ---------------------------------------------------------------------------
// bf16 MFMA GEMM (m97 structure): C[M,N] = A[M,K] * B[N,K]^T, fp32 out.
// 128x128 tile, BK=32, 4 waves (2x2) of 64x64, 16x16x32 MFMA, acc 4x4.
// M%128==0, N%128==0, K%32==0.
// ---------------------------------------------------------------------------
__global__ __launch_bounds__(256)
void gemm_bf16(const ushort_t* __restrict__ A,
               const ushort_t* __restrict__ B,
               float* __restrict__ C, int M, int N, int K)
{
    __shared__ ushort_t As[128 * 32];   // row-major [128][32], 8 KB
    __shared__ ushort_t Bs[128 * 32];

    const int tid  = threadIdx.x;
    const int wid  = tid >> 6;
    const int lane = tid & 63;
    const int m0 = blockIdx.x * 128;
    const int n0 = blockIdx.y * 128;
    const int wr = (wid >> 1) * 64;     // wave row offset in tile
    const int wc = (wid & 1) * 64;      // wave col offset in tile
    const int lr = lane & 15;           // fragment row
    const int lk = (lane >> 4) * 8;     // fragment k offset (elements)

    f32x4 acc[4][4];
#pragma unroll
    for (int m = 0; m < 4; m++)
#pragma unroll
        for (int n = 0; n < 4; n++)
            acc[m][n] = (f32x4){0.f, 0.f, 0.f, 0.f};

    for (int k0 = 0; k0 < K; k0 += 32) {
        __syncthreads();   // previous iter's ds_reads complete before overwrite
#pragma unroll
        for (int j = 0; j < 2; j++) {
            const int o   = j * 4096 + tid * 16;   // byte offset in LDS tile
            const int row = o >> 6;                // 64 B per row
            const int kk  = (o & 63) >> 1;         // element offset in k
            __builtin_amdgcn_global_load_lds(
                (const __attribute__((address_space(1))) uint_t*)(A + (size_t)(m0 + row) * K + k0 + kk),
                (__attribute__((address_space(3))) uint_t*)((char*)As + o),
                16, 0, 0);
            __builtin_amdgcn_global_load_lds(
                (const __attribute__((address_space(1))) uint_t*)(B + (size_t)(n0 + row) * K + k0 + kk),
                (__attribute__((address_space(3))) uint_t*)((char*)Bs + o),
                16, 0, 0);
        }
        __syncthreads();   // compiler drains vmcnt(0) before barrier

        bf16x8 af[4], bfr[4];
#pragma unroll
        for (int m = 0; m < 4; m++)
            af[m] = *(const bf16x8*)&As[(wr + m * 16 + lr) * 32 + lk];
#pragma unroll
        for (int n = 0; n < 4; n++)
            bfr[n] = *(const bf16x8*)&Bs[(wc + n * 16 + lr) * 32 + lk];
#pragma unroll
        for (int m = 0; m < 4; m++)
#pragma unroll
            for (int n = 0; n < 4; n++)
                acc[m][n] = __builtin_amdgcn_mfma_f32_16x16x32_bf16(af[m], bfr[n], acc[m][n], 0, 0, 0);
    }

    // epilogue: D layout col = lane&15, row = (lane>>4)*4 + reg
    const int er = (lane >> 4) * 4;
    const int ec = lane & 15;
#pragma unroll
    for (int m = 0; m < 4; m++) {
        const int grow = m0 + wr + m * 16 + er;
#pragma unroll
        for (int n = 0; n < 4; n++) {
            const int gcol = n0 + wc + n * 16 + ec;
#pragma unroll
            for (int r = 0; r < 4; r++)
                C[(size_t)(grow + r) * N + gcol] = acc[m][n][r];
        }
    }
}

// ---------------------------------------------------------------------------
// 64x64 tile fp32 GEMM, optional split-K (atomicAdd) / bias+softplus epilogue
// ---------------------------------------------------------------------------
template<int EPI, int SPLITK>
__global__ __launch_bounds__(256)
void gemm64(const float* __restrict__ A, int lda,
            const float* __restrict__ B, int ldb,
            float* C, int ldc,
            const float* __restrict__ bias,
            int M, int N, int K, int KC)
{
    __shared__ float As[16][68];
    __shared__ float Bs[16][68];
    const int tid = threadIdx.x;
    const int m0 = blockIdx.x * 64;
    const int n0 = blockIdx.y * 64;
    const int kbeg = SPLITK ? blockIdx.z * KC : 0;
    const int kend = SPLITK ? min(K, kbeg + KC) : K;
    const int lr = tid >> 2;
    const int lq = (tid & 3) * 4;
    const int tm = tid >> 4;
    const int tn = tid & 15;

    float acc[4][4];
#pragma unroll
    for (int i = 0; i < 4; i++)
#pragma unroll
        for (int j = 0; j < 4; j++) acc[i][j] = 0.f;

    const bool am = (m0 + lr) < M;
    const bool bn = (n0 + lr) < N;
    const float* Arow = A + (size_t)(m0 + lr) * lda;
    const float* Brow = B + (size_t)(n0 + lr) * ldb;

    for (int k0 = kbeg; k0 < kend; k0 += 16) {
        float4 va = am ? *(const float4*)(Arow + k0 + lq) : make_float4(0,0,0,0);
        float4 vb = bn ? *(const float4*)(Brow + k0 + lq) : make_float4(0,0,0,0);
        __syncthreads();
        As[lq+0][lr]=va.x; As[lq+1][lr]=va.y; As[lq+2][lr]=va.z; As[lq+3][lr]=va.w;
        Bs[lq+0][lr]=vb.x; Bs[lq+1][lr]=vb.y; Bs[lq+2][lr]=vb.z; Bs[lq+3][lr]=vb.w;
        __syncthreads();
#pragma unroll
        for (int kk = 0; kk < 16; kk++) {
            float a_[4], b_[4];
#pragma unroll
            for (int i = 0; i < 4; i++) { a_[i] = As[kk][tm*4+i]; b_[i] = Bs[kk][tn*4+i]; }
#pragma unroll
            for (int i = 0; i < 4; i++)
#pragma unroll
                for (int j = 0; j < 4; j++)
                    acc[i][j] = fmaf(a_[i], b_[j], acc[i][j]);
        }
    }

#pragma unroll
    for (int i = 0; i < 4; i++) {
        int m = m0 + tm*4 + i;
        if (m >= M) continue;
#pragma unroll
        for (int j = 0; j < 4; j++) {
            int n = n0 + tn*4 + j;
            if (n >= N) continue;
            float c = acc[i][j];
            if (SPLITK) {
                atomicAdd(&C[(size_t)m * ldc + n], c);
            } else {
                if (EPI == 1) {
                    c += bias[n];
                    c = (c > 20.f) ? c : log1pf(__expf(c));
                }
                C[(size_t)m * ldc + n] = c;
            }
        }
    }
}

// ---------------------------------------------------------------------------
// Depthwise causal conv (width 4) + bias + SiLU.
// ---------------------------------------------------------------------------
__global__ __launch_bounds__(256)
void conv_silu_kernel(const float* __restrict__ xz,
                      const float* __restrict__ conv_w,
                      const float* __restrict__ conv_b,
                      float* __restrict__ xc)
{
    int idx = blockIdx.x * 256 + threadIdx.x;
    if (idx >= LSEQ * DINNER) return;
    int t = idx / DINNER;
    int d = idx - t * DINNER;
    float acc = conv_b[d];
#pragma unroll
    for (int j = 0; j < 4; j++) {
        int tt = t - 3 + j;
        if (tt >= 0) acc = fmaf(conv_w[d*4 + j], xz[(size_t)tt * (2*DINNER) + d], acc);
    }
    xc[idx] = siluf(acc);
}

// ---------------------------------------------------------------------------
// Chunked parallel selective scan (3 phases). Phase 3 writes y as bf16.
// ---------------------------------------------------------------------------
__global__ __launch_bounds__(256)
void scan_phase1(const float* __restrict__ dtm,
                 const float* __restrict__ xdbl,
                 const float* __restrict__ xc,
                 const float* __restrict__ A_log,
                 float* __restrict__ Aprod, float* __restrict__ hend)
{
    const int tid = threadIdx.x;
    const int n = tid & 15;
    const int d = blockIdx.x * 16 + (tid >> 4);
    const int c = blockIdx.y;
    const float a_ = -__expf(A_log[d * DSTATE + n]);
    float h = 0.f, Ap = 1.f;
    const int t0 = c * CL;
#pragma unroll 4
    for (int t = t0; t < t0 + CL; t++) {
        float dtv = dtm[(size_t)t * DINNER + d];
        float xv  = xc[(size_t)t * DINNER + d];
        float Bv  = xdbl[t * XCOLS + DTRANK + n];
        float e = __expf(dtv * a_);
        h = fmaf(e, h, dtv * Bv * xv);
        Ap *= e;
    }
    const size_t idx = (size_t)c * SSTATE + d * DSTATE + n;
    Aprod[idx] = Ap;
    hend[idx]  = h;
}

__global__ __launch_bounds__(256)
void scan_phase2(const float* __restrict__ Aprod, float* __restrict__ hend)
{
    const int idx = blockIdx.x * 256 + threadIdx.x;
    float carry = 0.f;
#pragma unroll
    for (int c = 0; c < NC; c++) {
        const size_t k = (size_t)c * SSTATE + idx;
        float oh = hend[k];
        float oA = Aprod[k];
        hend[k] = carry;
        carry = fmaf(oA, carry, oh);
    }
}

__global__ __launch_bounds__(256)
void scan_phase3(const float* __restrict__ dtm,
                 const float* __restrict__ xdbl,
                 const float* __restrict__ xcin,
                 const float* __restrict__ A_log,
                 const float* __restrict__ Dp,
                 const float* __restrict__ xz,
                 const float* __restrict__ hinit,
                 ushort_t* __restrict__ yb)
{
    const int tid = threadIdx.x;
    const int n = tid & 15;
    const int d = blockIdx.x * 16 + (tid >> 4);
    const int c = blockIdx.y;
    const float a_ = -__expf(A_log[d * DSTATE + n]);
    const float Dv = Dp[d];
    float h = hinit[(size_t)c * SSTATE + d * DSTATE + n];
    const int t0 = c * CL;
    for (int t = t0; t < t0 + CL; t++) {
        float dtv = dtm[(size_t)t * DINNER + d];
        float xv  = xcin[(size_t)t * DINNER + d];
        float Bv  = xdbl[t * XCOLS + DTRANK + n];
        float Cv  = xdbl[t * XCOLS + DTRANK + DSTATE + n];
        h = fmaf(__expf(dtv * a_), h, dtv * Bv * xv);
        float p = h * Cv;
        p += __shfl_xor(p, 1);
        p += __shfl_xor(p, 2);
        p += __shfl_xor(p, 4);
        p += __shfl_xor(p, 8);
        if (n == 0) {
            float zv = xz[(size_t)t * (2*DINNER) + DINNER + d];
            yb[(size_t)t * DINNER + d] = f2bf((p + Dv * xv) * siluf(zv));
        }
    }
}

// ---------------------------------------------------------------------------
extern "C" void kernel_launch(void* const* d_in, const int* in_sizes, int n_in,
                              void* d_out, int out_size, void* d_ws, size_t ws_size,
                              hipStream_t stream)
{
    const float* x      = (const float*)d_in[0];
    const float* W_in   = (const float*)d_in[1];
    const float* conv_w = (const float*)d_in[2];
    const float* conv_b = (const float*)d_in[3];
    const float* W_x    = (const float*)d_in[4];
    const float* W_dt   = (const float*)d_in[5];
    const float* b_dt   = (const float*)d_in[6];
    const float* A_log  = (const float*)d_in[7];
    const float* D_par  = (const float*)d_in[8];
    const float* W_out  = (const float*)d_in[9];
    float* out = (float*)d_out;
    float* ws  = (float*)d_ws;

    float* xz    = ws;                                   // 2048*4096 f32
    float* xc    = xz   + (size_t)LSEQ * 2 * DINNER;     // 2048*2048 f32
    float* xdbl  = xc   + (size_t)LSEQ * DINNER;         // 2048*96  f32
    float* dtm   = xdbl + (size_t)LSEQ * XCOLS;          // 2048*2048 f32
    float* Aprod = dtm  + (size_t)LSEQ * DINNER;         // 1M f32
    float* hend  = Aprod + (size_t)NC * SSTATE;          // 1M f32
    ushort_t* xb  = (ushort_t*)(hend + (size_t)NC * SSTATE);   // 2048*1024 bf16
    ushort_t* Wib = xb  + (size_t)LSEQ * DMODEL;               // 4096*1024 bf16
    ushort_t* Wob = Wib + (size_t)(2*DINNER) * DMODEL;         // 1024*2048 bf16
    ushort_t* yb  = Wob + (size_t)DMODEL * DINNER;             // 2048*2048 bf16

    // 0. casts to bf16
    hipLaunchKernelGGL(cast_bf16_kernel, dim3((LSEQ*DMODEL/8)/256), dim3(256), 0, stream,
                       x, xb, LSEQ*DMODEL);
    hipLaunchKernelGGL(cast_bf16_kernel, dim3((2*DINNER*DMODEL/8)/256), dim3(256), 0, stream,
                       W_in, Wib, 2*DINNER*DMODEL);
    hipLaunchKernelGGL(cast_bf16_kernel, dim3((DMODEL*DINNER/8)/256), dim3(256), 0, stream,
                       W_out, Wob, DMODEL*DINNER);

    // 1. in_proj: xz = x @ W_in^T   (2048 x 4096), bf16 MFMA
    hipLaunchKernelGGL(gemm_bf16, dim3(LSEQ/128, (2*DINNER)/128), dim3(256), 0, stream,
                       xb, Wib, xz, LSEQ, 2*DINNER, DMODEL);

    // 2. depthwise conv + SiLU -> xc
    hipLaunchKernelGGL(conv_silu_kernel, dim3((LSEQ*DINNER)/256), dim3(256), 0, stream,
                       xz, conv_w, conv_b, xc);

    // 3. x_dbl = xc @ W_x^T  (2048 x 96), fp32, split-K over 8 chunks
    hipMemsetAsync(xdbl, 0, (size_t)LSEQ * XCOLS * sizeof(float), stream);
    hipLaunchKernelGGL((gemm64<0,1>), dim3(LSEQ/64, 2, 8), dim3(256), 0, stream,
                       xc, DINNER, W_x, DINNER, xdbl, XCOLS, (const float*)nullptr,
                       LSEQ, XCOLS, DINNER, 256);

    // 4. dt = softplus(x_dbl[:, :64] @ W_dt^T + b_dt)  (2048 x 2048), fp32
    hipLaunchKernelGGL((gemm64<1,0>), dim3(LSEQ/64, DINNER/64, 1), dim3(256), 0, stream,
                       xdbl, XCOLS, W_dt, DTRANK, dtm, DINNER, b_dt,
                       LSEQ, DINNER, DTRANK, 0);

    // 5. chunked parallel scan; phase 3 writes y as bf16 (fused cast + gate)
    hipLaunchKernelGGL(scan_phase1, dim3(DINNER/16, NC), dim3(256), 0, stream,
                       dtm, xdbl, xc, A_log, Aprod, hend);
    hipLaunchKernelGGL(scan_phase2, dim3(SSTATE/256), dim3(256), 0, stream,
                       Aprod, hend);
    hipLaunchKernelGGL(scan_phase3, dim3(DINNER/16, NC), dim3(256), 0, stream,
                       dtm, xdbl, xc, A_log, D_par, xz, hend, yb);

    // 6. out = y @ W_out^T  (2048 x 1024), bf16 MFMA
    hipLaunchKernelGGL(gemm_bf16, dim3(LSEQ/128, DMODEL/128), dim3(256), 0, stream,
                       yb, Wob, out, LSEQ, DMODEL, DINNER);
}

// Round 4
// 223.730 us; speedup vs baseline: 9.2847x; 1.4352x over previous
//
#include <hip/hip_runtime.h>
#include <math.h>

#define LSEQ   2048
#define DMODEL 1024
#define DINNER 2048
#define DSTATE 16
#define DTRANK 64
#define XCOLS  96   // dt_rank + 2*d_state
#define CL     32   // scan chunk length
#define NC     (LSEQ/CL)          // 64 chunks
#define SSTATE (DINNER*DSTATE)    // 32768 scalar recurrences

typedef __attribute__((ext_vector_type(8))) short bf16x8;
typedef __attribute__((ext_vector_type(4))) float f32x4;
typedef unsigned short ushort_t;
typedef unsigned int uint_t;

__device__ __forceinline__ float siluf(float v) { return v / (1.f + __expf(-v)); }

// RNE float -> bf16 bits (finite inputs)
__device__ __forceinline__ ushort_t f2bf(float f) {
    uint_t u = __float_as_uint(f);
    u += 0x7FFFu + ((u >> 16) & 1u);
    return (ushort_t)(u >> 16);
}

// ---------------------------------------------------------------------------
// f32 -> bf16 cast, 8 elements/thread. n % 8 == 0.
// ---------------------------------------------------------------------------
__global__ __launch_bounds__(256)
void cast_bf16_kernel(const float* __restrict__ in, ushort_t* __restrict__ outp, int n)
{
    int i = (blockIdx.x * 256 + threadIdx.x) * 8;
    if (i >= n) return;
    float4 v0 = *(const float4*)(in + i);
    float4 v1 = *(const float4*)(in + i + 4);
    bf16x8 r;
    r[0] = (short)f2bf(v0.x); r[1] = (short)f2bf(v0.y);
    r[2] = (short)f2bf(v0.z); r[3] = (short)f2bf(v0.w);
    r[4] = (short)f2bf(v1.x); r[5] = (short)f2bf(v1.y);
    r[6] = (short)f2bf(v1.z); r[7] = (short)f2bf(v1.w);
    *(bf16x8*)(outp + i) = r;
}

// ---------------------------------------------------------------------------
// bf16 MFMA GEMM (m97 structure): C[M,N] = A[M,K] * B[N,K]^T, fp32 out.
// ---------------------------------------------------------------------------
__global__ __launch_bounds__(256)
void gemm_bf16(const ushort_t* __restrict__ A,
               const ushort_t* __restrict__ B,
               float* __restrict__ C, int M, int N, int K)
{
    __shared__ ushort_t As[128 * 32];
    __shared__ ushort_t Bs[128 * 32];

    const int tid  = threadIdx.x;
    const int wid  = tid >> 6;
    const int lane = tid & 63;
    const int m0 = blockIdx.x * 128;
    const int n0 = blockIdx.y * 128;
    const int wr = (wid >> 1) * 64;
    const int wc = (wid & 1) * 64;
    const int lr = lane & 15;
    const int lk = (lane >> 4) * 8;

    f32x4 acc[4][4];
#pragma unroll
    for (int m = 0; m < 4; m++)
#pragma unroll
        for (int n = 0; n < 4; n++)
            acc[m][n] = (f32x4){0.f, 0.f, 0.f, 0.f};

    for (int k0 = 0; k0 < K; k0 += 32) {
        __syncthreads();
#pragma unroll
        for (int j = 0; j < 2; j++) {
            const int o   = j * 4096 + tid * 16;
            const int row = o >> 6;
            const int kk  = (o & 63) >> 1;
            __builtin_amdgcn_global_load_lds(
                (const __attribute__((address_space(1))) uint_t*)(A + (size_t)(m0 + row) * K + k0 + kk),
                (__attribute__((address_space(3))) uint_t*)((char*)As + o),
                16, 0, 0);
            __builtin_amdgcn_global_load_lds(
                (const __attribute__((address_space(1))) uint_t*)(B + (size_t)(n0 + row) * K + k0 + kk),
                (__attribute__((address_space(3))) uint_t*)((char*)Bs + o),
                16, 0, 0);
        }
        __syncthreads();

        bf16x8 af[4], bfr[4];
#pragma unroll
        for (int m = 0; m < 4; m++)
            af[m] = *(const bf16x8*)&As[(wr + m * 16 + lr) * 32 + lk];
#pragma unroll
        for (int n = 0; n < 4; n++)
            bfr[n] = *(const bf16x8*)&Bs[(wc + n * 16 + lr) * 32 + lk];
#pragma unroll
        for (int m = 0; m < 4; m++)
#pragma unroll
            for (int n = 0; n < 4; n++)
                acc[m][n] = __builtin_amdgcn_mfma_f32_16x16x32_bf16(af[m], bfr[n], acc[m][n], 0, 0, 0);
    }

    const int er = (lane >> 4) * 4;
    const int ec = lane & 15;
#pragma unroll
    for (int m = 0; m < 4; m++) {
        const int grow = m0 + wr + m * 16 + er;
#pragma unroll
        for (int n = 0; n < 4; n++) {
            const int gcol = n0 + wc + n * 16 + ec;
#pragma unroll
            for (int r = 0; r < 4; r++)
                C[(size_t)(grow + r) * N + gcol] = acc[m][n][r];
        }
    }
}

// ---------------------------------------------------------------------------
// 64x64 tile fp32 GEMM, optional split-K (atomicAdd) / bias+softplus epilogue
// ---------------------------------------------------------------------------
template<int EPI, int SPLITK>
__global__ __launch_bounds__(256)
void gemm64(const float* __restrict__ A, int lda,
            const float* __restrict__ B, int ldb,
            float* C, int ldc,
            const float* __restrict__ bias,
            int M, int N, int K, int KC)
{
    __shared__ float As[16][68];
    __shared__ float Bs[16][68];
    const int tid = threadIdx.x;
    const int m0 = blockIdx.x * 64;
    const int n0 = blockIdx.y * 64;
    const int kbeg = SPLITK ? blockIdx.z * KC : 0;
    const int kend = SPLITK ? min(K, kbeg + KC) : K;
    const int lr = tid >> 2;
    const int lq = (tid & 3) * 4;
    const int tm = tid >> 4;
    const int tn = tid & 15;

    float acc[4][4];
#pragma unroll
    for (int i = 0; i < 4; i++)
#pragma unroll
        for (int j = 0; j < 4; j++) acc[i][j] = 0.f;

    const bool am = (m0 + lr) < M;
    const bool bn = (n0 + lr) < N;
    const float* Arow = A + (size_t)(m0 + lr) * lda;
    const float* Brow = B + (size_t)(n0 + lr) * ldb;

    for (int k0 = kbeg; k0 < kend; k0 += 16) {
        float4 va = am ? *(const float4*)(Arow + k0 + lq) : make_float4(0,0,0,0);
        float4 vb = bn ? *(const float4*)(Brow + k0 + lq) : make_float4(0,0,0,0);
        __syncthreads();
        As[lq+0][lr]=va.x; As[lq+1][lr]=va.y; As[lq+2][lr]=va.z; As[lq+3][lr]=va.w;
        Bs[lq+0][lr]=vb.x; Bs[lq+1][lr]=vb.y; Bs[lq+2][lr]=vb.z; Bs[lq+3][lr]=vb.w;
        __syncthreads();
#pragma unroll
        for (int kk = 0; kk < 16; kk++) {
            float a_[4], b_[4];
#pragma unroll
            for (int i = 0; i < 4; i++) { a_[i] = As[kk][tm*4+i]; b_[i] = Bs[kk][tn*4+i]; }
#pragma unroll
            for (int i = 0; i < 4; i++)
#pragma unroll
                for (int j = 0; j < 4; j++)
                    acc[i][j] = fmaf(a_[i], b_[j], acc[i][j]);
        }
    }

#pragma unroll
    for (int i = 0; i < 4; i++) {
        int m = m0 + tm*4 + i;
        if (m >= M) continue;
#pragma unroll
        for (int j = 0; j < 4; j++) {
            int n = n0 + tn*4 + j;
            if (n >= N) continue;
            float c = acc[i][j];
            if (SPLITK) {
                atomicAdd(&C[(size_t)m * ldc + n], c);
            } else {
                if (EPI == 1) {
                    c += bias[n];
                    c = (c > 20.f) ? c : log1pf(__expf(c));
                }
                C[(size_t)m * ldc + n] = c;
            }
        }
    }
}

// ---------------------------------------------------------------------------
// Depthwise causal conv (width 4) + bias + SiLU.
// ---------------------------------------------------------------------------
__global__ __launch_bounds__(256)
void conv_silu_kernel(const float* __restrict__ xz,
                      const float* __restrict__ conv_w,
                      const float* __restrict__ conv_b,
                      float* __restrict__ xc)
{
    int idx = blockIdx.x * 256 + threadIdx.x;
    if (idx >= LSEQ * DINNER) return;
    int t = idx / DINNER;
    int d = idx - t * DINNER;
    float acc = conv_b[d];
#pragma unroll
    for (int j = 0; j < 4; j++) {
        int tt = t - 3 + j;
        if (tt >= 0) acc = fmaf(conv_w[d*4 + j], xz[(size_t)tt * (2*DINNER) + d], acc);
    }
    xc[idx] = siluf(acc);
}

// ---------------------------------------------------------------------------
// Chunked parallel selective scan, lane-owns-channel layout.
// Per lane: one d, h[16]/a[16] in registers. B/C broadcast via LDS chunk tile.
// Storage layout for chunk boundaries: [c][n][d] (coalesced across lanes).
// Phase 1: local scan from 0 -> hend; Aprod = exp(a_n * sum(dt)).
// Phase 2: sequential over NC chunks: hend[c] <- carry-in of chunk c.
// Phase 3: re-scan from carry-in; y = sum_n h*C; gate+D-skip; bf16 store.
// ---------------------------------------------------------------------------
__global__ __launch_bounds__(256)
void scan_phase1(const float* __restrict__ dtm,
                 const float* __restrict__ xdbl,
                 const float* __restrict__ xc,
                 const float* __restrict__ A_log,
                 float* __restrict__ Aprod, float* __restrict__ hend)
{
    __shared__ float Bs[CL][16];
    const int tid = threadIdx.x;
    const int d = blockIdx.x * 256 + tid;
    const int c = blockIdx.y;
    const int t0 = c * CL;

    // stage B chunk tile: CL*16 = 512 floats, 2/thread
    {
        int t = tid >> 3, n = (tid * 2) & 15;
        float2 v = *(const float2*)&xdbl[(size_t)(t0 + t) * XCOLS + DTRANK + n];
        Bs[t][n] = v.x; Bs[t][n + 1] = v.y;
    }

    float a[16];
#pragma unroll
    for (int q = 0; q < 4; q++) {
        f32x4 v = *(const f32x4*)&A_log[(size_t)d * DSTATE + q * 4];
#pragma unroll
        for (int j = 0; j < 4; j++) a[q * 4 + j] = -__expf(v[j]);
    }
    float h[16];
#pragma unroll
    for (int n = 0; n < 16; n++) h[n] = 0.f;
    float sdt = 0.f;

    __syncthreads();

    float dtv = dtm[(size_t)t0 * DINNER + d];
    float xv  = xc[(size_t)t0 * DINNER + d];
    for (int tt = 0; tt < CL; tt++) {
        // prefetch next t (clamped; harmless redundant load at chunk end)
        int tn_ = t0 + ((tt + 1 < CL) ? tt + 1 : tt);
        float dtv_n = dtm[(size_t)tn_ * DINNER + d];
        float xv_n  = xc[(size_t)tn_ * DINNER + d];

        f32x4 Bq[4];
#pragma unroll
        for (int q = 0; q < 4; q++) Bq[q] = *(const f32x4*)&Bs[tt][q * 4];
        float dtx = dtv * xv;
        sdt += dtv;
#pragma unroll
        for (int n = 0; n < 16; n++) {
            float e = __expf(dtv * a[n]);
            h[n] = fmaf(e, h[n], dtx * Bq[n >> 2][n & 3]);
        }
        dtv = dtv_n; xv = xv_n;
    }

#pragma unroll
    for (int n = 0; n < 16; n++) {
        const size_t k = (size_t)c * SSTATE + (size_t)n * DINNER + d;
        hend[k]  = h[n];
        Aprod[k] = __expf(a[n] * sdt);
    }
}

__global__ __launch_bounds__(256)
void scan_phase2(const float* __restrict__ Aprod, float* __restrict__ hend)
{
    const int idx = blockIdx.x * 256 + threadIdx.x;   // 0..SSTATE-1
    float carry = 0.f;
#pragma unroll
    for (int c = 0; c < NC; c++) {
        const size_t k = (size_t)c * SSTATE + idx;
        float oh = hend[k];
        float oA = Aprod[k];
        hend[k] = carry;
        carry = fmaf(oA, carry, oh);
    }
}

__global__ __launch_bounds__(256)
void scan_phase3(const float* __restrict__ dtm,
                 const float* __restrict__ xdbl,
                 const float* __restrict__ xc,
                 const float* __restrict__ A_log,
                 const float* __restrict__ Dp,
                 const float* __restrict__ xz,
                 const float* __restrict__ hinit,
                 ushort_t* __restrict__ yb)
{
    __shared__ float Bs[CL][16];
    __shared__ float Cs[CL][16];
    const int tid = threadIdx.x;
    const int d = blockIdx.x * 256 + tid;
    const int c = blockIdx.y;
    const int t0 = c * CL;

    // stage B and C chunk tiles: 2 * CL*16 floats; threads 0..127 -> B, 128.. -> C
    {
        int r = tid & 127;
        int t = r >> 2, n = (r * 4) & 15;
        const float* src = &xdbl[(size_t)(t0 + t) * XCOLS + DTRANK + ((tid < 128) ? 0 : DSTATE) + n];
        float4 v = *(const float4*)src;
        float* dst = (tid < 128) ? &Bs[t][n] : &Cs[t][n];
        dst[0] = v.x; dst[1] = v.y; dst[2] = v.z; dst[3] = v.w;
    }

    float a[16];
#pragma unroll
    for (int q = 0; q < 4; q++) {
        f32x4 v = *(const f32x4*)&A_log[(size_t)d * DSTATE + q * 4];
#pragma unroll
        for (int j = 0; j < 4; j++) a[q * 4 + j] = -__expf(v[j]);
    }
    const float Dv = Dp[d];
    float h[16];
#pragma unroll
    for (int n = 0; n < 16; n++)
        h[n] = hinit[(size_t)c * SSTATE + (size_t)n * DINNER + d];

    __syncthreads();

    float dtv = dtm[(size_t)t0 * DINNER + d];
    float xv  = xc[(size_t)t0 * DINNER + d];
    for (int tt = 0; tt < CL; tt++) {
        const int t = t0 + tt;
        int tn_ = t0 + ((tt + 1 < CL) ? tt + 1 : tt);
        float dtv_n = dtm[(size_t)tn_ * DINNER + d];
        float xv_n  = xc[(size_t)tn_ * DINNER + d];
        float zv    = xz[(size_t)t * (2 * DINNER) + DINNER + d];

        f32x4 Bq[4], Cq[4];
#pragma unroll
        for (int q = 0; q < 4; q++) {
            Bq[q] = *(const f32x4*)&Bs[tt][q * 4];
            Cq[q] = *(const f32x4*)&Cs[tt][q * 4];
        }
        float dtx = dtv * xv;
        float y = 0.f;
#pragma unroll
        for (int n = 0; n < 16; n++) {
            float e = __expf(dtv * a[n]);
            h[n] = fmaf(e, h[n], dtx * Bq[n >> 2][n & 3]);
            y = fmaf(h[n], Cq[n >> 2][n & 3], y);
        }
        yb[(size_t)t * DINNER + d] = f2bf((y + Dv * xv) * siluf(zv));
        dtv = dtv_n; xv = xv_n;
    }
}

// ---------------------------------------------------------------------------
extern "C" void kernel_launch(void* const* d_in, const int* in_sizes, int n_in,
                              void* d_out, int out_size, void* d_ws, size_t ws_size,
                              hipStream_t stream)
{
    const float* x      = (const float*)d_in[0];
    const float* W_in   = (const float*)d_in[1];
    const float* conv_w = (const float*)d_in[2];
    const float* conv_b = (const float*)d_in[3];
    const float* W_x    = (const float*)d_in[4];
    const float* W_dt   = (const float*)d_in[5];
    const float* b_dt   = (const float*)d_in[6];
    const float* A_log  = (const float*)d_in[7];
    const float* D_par  = (const float*)d_in[8];
    const float* W_out  = (const float*)d_in[9];
    float* out = (float*)d_out;
    float* ws  = (float*)d_ws;

    float* xz    = ws;                                   // 2048*4096 f32
    float* xc    = xz   + (size_t)LSEQ * 2 * DINNER;     // 2048*2048 f32
    float* xdbl  = xc   + (size_t)LSEQ * DINNER;         // 2048*96  f32
    float* dtm   = xdbl + (size_t)LSEQ * XCOLS;          // 2048*2048 f32
    float* Aprod = dtm  + (size_t)LSEQ * DINNER;         // NC*SSTATE f32
    float* hend  = Aprod + (size_t)NC * SSTATE;          // NC*SSTATE f32
    ushort_t* xb  = (ushort_t*)(hend + (size_t)NC * SSTATE);   // 2048*1024 bf16
    ushort_t* Wib = xb  + (size_t)LSEQ * DMODEL;               // 4096*1024 bf16
    ushort_t* Wob = Wib + (size_t)(2*DINNER) * DMODEL;         // 1024*2048 bf16
    ushort_t* yb  = Wob + (size_t)DMODEL * DINNER;             // 2048*2048 bf16

    // 0. casts to bf16
    hipLaunchKernelGGL(cast_bf16_kernel, dim3((LSEQ*DMODEL/8)/256), dim3(256), 0, stream,
                       x, xb, LSEQ*DMODEL);
    hipLaunchKernelGGL(cast_bf16_kernel, dim3((2*DINNER*DMODEL/8)/256), dim3(256), 0, stream,
                       W_in, Wib, 2*DINNER*DMODEL);
    hipLaunchKernelGGL(cast_bf16_kernel, dim3((DMODEL*DINNER/8)/256), dim3(256), 0, stream,
                       W_out, Wob, DMODEL*DINNER);

    // 1. in_proj: xz = x @ W_in^T   (2048 x 4096), bf16 MFMA
    hipLaunchKernelGGL(gemm_bf16, dim3(LSEQ/128, (2*DINNER)/128), dim3(256), 0, stream,
                       xb, Wib, xz, LSEQ, 2*DINNER, DMODEL);

    // 2. depthwise conv + SiLU -> xc
    hipLaunchKernelGGL(conv_silu_kernel, dim3((LSEQ*DINNER)/256), dim3(256), 0, stream,
                       xz, conv_w, conv_b, xc);

    // 3. x_dbl = xc @ W_x^T  (2048 x 96), fp32, split-K over 8 chunks
    hipMemsetAsync(xdbl, 0, (size_t)LSEQ * XCOLS * sizeof(float), stream);
    hipLaunchKernelGGL((gemm64<0,1>), dim3(LSEQ/64, 2, 8), dim3(256), 0, stream,
                       xc, DINNER, W_x, DINNER, xdbl, XCOLS, (const float*)nullptr,
                       LSEQ, XCOLS, DINNER, 256);

    // 4. dt = softplus(x_dbl[:, :64] @ W_dt^T + b_dt)  (2048 x 2048), fp32
    hipLaunchKernelGGL((gemm64<1,0>), dim3(LSEQ/64, DINNER/64, 1), dim3(256), 0, stream,
                       xdbl, XCOLS, W_dt, DTRANK, dtm, DINNER, b_dt,
                       LSEQ, DINNER, DTRANK, 0);

    // 5. chunked parallel scan (lane-owns-channel); phase 3 writes bf16 y
    hipLaunchKernelGGL(scan_phase1, dim3(DINNER/256, NC), dim3(256), 0, stream,
                       dtm, xdbl, xc, A_log, Aprod, hend);
    hipLaunchKernelGGL(scan_phase2, dim3(SSTATE/256), dim3(256), 0, stream,
                       Aprod, hend);
    hipLaunchKernelGGL(scan_phase3, dim3(DINNER/256, NC), dim3(256), 0, stream,
                       dtm, xdbl, xc, A_log, D_par, xz, hend, yb);

    // 6. out = y @ W_out^T  (2048 x 1024), bf16 MFMA
    hipLaunchKernelGGL(gemm_bf16, dim3(LSEQ/128, DMODEL/128), dim3(256), 0, stream,
                       yb, Wob, out, LSEQ, DMODEL, DINNER);
}